// Round 1
// baseline (2698.096 us; speedup 1.0000x reference)
//
#include <hip/hip_runtime.h>
#include <stdint.h>

#define BB 4
#define NN 16384
#define NPOINT 1024
#define NSAMPLE 32
#define CC 64
#define RADIUS2 0.00999999977648258209228515625f
#define BIGF 1.0e10f

// ---- FPS decomposition: FKB one-wave blocks per batch, device-scope exchange
#define FKB 32              // blocks per batch
#define FPTS (NN / FKB)     // 512 points per block
#define FWT 64              // 1 wave per block

typedef float f32x2 __attribute__((ext_vector_type(2)));

__device__ __forceinline__ f32x2 pk_add(f32x2 a, f32x2 b) {
    f32x2 d;
    asm("v_pk_add_f32 %0, %1, %2" : "=v"(d) : "v"(a), "v"(b));
    return d;
}
__device__ __forceinline__ f32x2 pk_mul(f32x2 a, f32x2 b) {
    f32x2 d;
    asm("v_pk_mul_f32 %0, %1, %2" : "=v"(d) : "v"(a), "v"(b));
    return d;
}

// ---------------- repack w1 (64x67) -> (64x68) padded, pad=0 ----------------
// Also zeroes the FPS exchange slots (2 parities * BB * FKB = 256 u64) so the
// generation tags never alias a previous run's (workspace may be poisoned).
__global__ __launch_bounds__(256) void repack_w1(const float* __restrict__ w1,
                                                 float* __restrict__ w1p,
                                                 unsigned long long* __restrict__ slots) {
    int t = threadIdx.x;
    for (int i = t; i < 64 * 68; i += 256) {
        int o = i / 68, c = i % 68;
        w1p[i] = (c < 67) ? w1[o * 67 + c] : 0.0f;
    }
    slots[t] = 0ull;  // exactly 256 entries
}

// DPP-based argmax step (max value, min index on ties) — validated bit-exact.
template <int CTRL>
__device__ __forceinline__ void amax_step(float& v, int& i) {
    int nv = __builtin_amdgcn_update_dpp(__float_as_int(v), __float_as_int(v),
                                         CTRL, 0xf, 0xf, false);
    int ni = __builtin_amdgcn_update_dpp(i, i, CTRL, 0xf, 0xf, false);
    float fv = __int_as_float(nv);
    if (fv > v || (fv == v && ni < i)) { v = fv; i = ni; }
}
__device__ __forceinline__ void wave_amax(float& v, int& i) {
    amax_step<0x111>(v, i);  // row_shr:1
    amax_step<0x112>(v, i);  // row_shr:2
    amax_step<0x114>(v, i);  // row_shr:4
    amax_step<0x118>(v, i);  // row_shr:8
    amax_step<0x142>(v, i);  // row_bcast:15
    amax_step<0x143>(v, i);  // row_bcast:31  -> lane63 holds full wave result
}

#define PAIR4(X) X(0) X(1) X(2) X(3)

// ---------------- FPS: FKB one-wave blocks per batch ----------------
// Previous version: 1 block/batch -> 4 CUs busy, VALUBusy ~71% on the active
// CUs (1.11% global * 256/4), 2.12us/iter. Now the per-iteration distance
// update is spread over 32 CUs per batch; blocks exchange their local argmax
// candidate via one 64-bit AGENT-scope atomic per block per iteration:
//   slot = [ (iter+1)<<14 | global_idx ]<<32 | fp32(value)
// Parity double-buffered slots bound the skew at 1 iteration (a block can only
// advance past iter i after ALL blocks published iter i, so a gen i+2 write
// never lands on a slot still being polled for gen i). Every block reduces the
// 32 candidates redundantly with the validated (max value, min index) rule ->
// identical winner everywhere, no second broadcast round.
// NOTE: deliberately NO __restrict__ on xyz/new_xyz (prior sessions: restrict
// makes the coord loads invariant and LLVM rematerializes them from memory
// every iteration instead of keeping them register-resident).
__global__ __launch_bounds__(FWT)
void fps_kernel(const float* xyz, float* new_xyz,
                unsigned long long* slots) {
    const int bid = blockIdx.x;
    const int b = bid >> 5;    // FKB == 32
    const int kb = bid & 31;
    const int lane = threadIdx.x;  // 0..63

    const float* xb = xyz + (size_t)b * NN * 3;
    const int pbase = kb * FPTS;

#define DECL(k) f32x2 px##k, py##k, pz##k, dd##k;
    PAIR4(DECL)
#undef DECL

    // pair k covers global points pbase + 2*(k*FWT + lane) and +1
#define LOAD(k) {                                                   \
        const float* p = xb + (size_t)3 * pbase                     \
                            + (size_t)6 * (k * FWT + lane);         \
        f32x2 a = *(const f32x2*)(p + 0);                           \
        f32x2 bq = *(const f32x2*)(p + 2);                          \
        f32x2 c = *(const f32x2*)(p + 4);                           \
        px##k.x = a.x;  py##k.x = a.y;  pz##k.x = bq.x;             \
        px##k.y = bq.y; py##k.y = c.x;  pz##k.y = c.y;              \
        dd##k.x = BIGF; dd##k.y = BIGF;                             \
    }
    PAIR4(LOAD)
#undef LOAD

    // initial centroid = point 0
    float cx = xb[0], cy = xb[1], cz = xb[2];

    for (int i = 0; i < NPOINT; ++i) {
        if (kb == 0 && lane == 0) {
            float* o = new_xyz + ((size_t)b * NPOINT + i) * 3;
            o[0] = cx; o[1] = cy; o[2] = cz;
        }
        if (i == NPOINT - 1) break;  // last centroid written; no next needed

        f32x2 ncx, ncy, ncz;
        ncx.x = -cx; ncx.y = -cx;
        ncy.x = -cy; ncy.y = -cy;
        ncz.x = -cz; ncz.y = -cz;

        float bv = -1.0f;
        int bj = 0;
        // EXACT numpy semantics per element: sub = a+(-b); products rounded
        // individually; sum order (x^2+y^2)+z^2; min; running max with strict
        // > and ascending local slot -> first-occurrence tie-break.
#define STEP(k) {                                                   \
        f32x2 dx = pk_add(px##k, ncx);                              \
        f32x2 dy = pk_add(py##k, ncy);                              \
        f32x2 dz = pk_add(pz##k, ncz);                              \
        f32x2 m0 = pk_mul(dx, dx);                                  \
        f32x2 m1 = pk_mul(dy, dy);                                  \
        f32x2 m2 = pk_mul(dz, dz);                                  \
        f32x2 d  = pk_add(pk_add(m0, m1), m2);                      \
        dd##k.x = fminf(dd##k.x, d.x);                              \
        dd##k.y = fminf(dd##k.y, d.y);                              \
        if (dd##k.x > bv) { bv = dd##k.x; bj = 2 * k; }             \
        if (dd##k.y > bv) { bv = dd##k.y; bj = 2 * k + 1; }         \
    }
        PAIR4(STEP)
#undef STEP
        // global index within batch; monotone in bj for fixed lane ->
        // in-thread first-occurrence holds
        int bi = pbase + (bj >> 1) * (2 * FWT) + 2 * lane + (bj & 1);

        wave_amax(bv, bi);

        unsigned long long* sb = slots + ((size_t)(i & 1) * BB + b) * FKB;
        if (lane == 63) {
            unsigned long long sv =
                ((unsigned long long)(((unsigned)(i + 1) << 14) | (unsigned)bi) << 32)
                | (unsigned long long)__float_as_uint(bv);
            __hip_atomic_store(&sb[kb], sv, __ATOMIC_RELAXED,
                               __HIP_MEMORY_SCOPE_AGENT);
        }

        // poll all FKB slots for this iteration's tag (lane l polls slot l)
        const unsigned want = (unsigned)(i + 1);
        unsigned long long s = 0;
        bool ready = (lane >= FKB);
        while (true) {
            if (!ready) {
                s = __hip_atomic_load(&sb[lane], __ATOMIC_RELAXED,
                                      __HIP_MEMORY_SCOPE_AGENT);
                ready = ((unsigned)(s >> 46)) == want;
            }
            if (__all(ready)) break;
        }

        float rv; int ri;
        if (lane < FKB) {
            rv = __uint_as_float((unsigned)s);
            ri = (int)((s >> 32) & 0x3FFFu);
        } else {
            rv = -1.0f;        // distances are >= 0, never wins
            ri = 0x7FFFFFFF;
        }
        wave_amax(rv, ri);
        int ixs = __builtin_amdgcn_readlane(ri, 63);  // uniform -> SGPR

        cx = xb[ixs * 3 + 0];
        cy = xb[ixs * 3 + 1];
        cz = xb[ixs * 3 + 2];
    }
}

// ---------------- ball query: one wave per centroid ----------------
__global__ __launch_bounds__(256) void ballquery_kernel(const float* __restrict__ xyz,
                                                        const float* __restrict__ new_xyz,
                                                        int* __restrict__ nidx) {
    const int t = threadIdx.x;
    const int lane = t & 63;
    const int w = t >> 6;
    const int cid = blockIdx.x * 4 + w;  // 0..4095
    const int b = cid >> 10;

    __shared__ int list[4][NSAMPLE];

    const float* xb = xyz + (size_t)b * NN * 3;
    const float* c = new_xyz + (size_t)cid * 3;
    float cx = c[0], cy = c[1], cz = c[2];

    int cnt = 0;
    for (int base = 0; base < NN && cnt < NSAMPLE; base += 64) {
        int j = base + lane;
        float dx = __fsub_rn(xb[j * 3 + 0], cx);
        float dy = __fsub_rn(xb[j * 3 + 1], cy);
        float dz = __fsub_rn(xb[j * 3 + 2], cz);
        float d2 = __fadd_rn(__fadd_rn(__fmul_rn(dx, dx), __fmul_rn(dy, dy)),
                             __fmul_rn(dz, dz));
        bool hit = d2 < RADIUS2;
        unsigned long long m = __ballot(hit);
        int pre = __popcll(m & ((1ull << lane) - 1ull));
        if (hit) {
            int pos = cnt + pre;
            if (pos < NSAMPLE) list[w][pos] = j;
        }
        cnt += __popcll(m);  // ballot result uniform -> cnt stays wave-uniform
    }
    __syncthreads();
    if (lane < NSAMPLE) {
        int first = list[w][0];  // >=1 hit always: centroid is a member point
        int v = (lane < cnt) ? list[w][lane] : first;
        nidx[(size_t)cid * NSAMPLE + lane] = v;
    }
}

// ---------------- grouped MLP + maxpool: one thread per (point,sample) ------
__global__ __launch_bounds__(256, 2) void mlp_kernel(
    const float* __restrict__ xyz, const float* __restrict__ features,
    const float* __restrict__ new_xyz, const int* __restrict__ nidx,
    const float* __restrict__ w1p, const float* __restrict__ b1,
    const float* __restrict__ w2, const float* __restrict__ b2,
    const float* __restrict__ w3, const float* __restrict__ b3,
    float* __restrict__ out) {
    const int gid = blockIdx.x * 256 + threadIdx.x;
    const int s = gid & 31;
    const int pg = gid >> 5;  // b*1024 + p
    const int b = pg >> 10;
    const int p = pg & 1023;

    const int idx = nidx[gid];
    const float* nc = new_xyz + (size_t)pg * 3;
    const float* pt = xyz + ((size_t)b * NN + idx) * 3;
    float gx = pt[0] - nc[0], gy = pt[1] - nc[1], gz = pt[2] - nc[2];

    float fin[64];
    const float4* fp = (const float4*)(features + ((size_t)b * NN + idx) * CC);
#pragma unroll
    for (int j = 0; j < 16; ++j) {
        float4 q = fp[j];
        fin[4 * j] = q.x; fin[4 * j + 1] = q.y;
        fin[4 * j + 2] = q.z; fin[4 * j + 3] = q.w;
    }

    float h1[64];
#pragma unroll
    for (int o = 0; o < 64; ++o) {
        const float4* wr = (const float4*)(w1p + o * 68);  // uniform -> s_load
        float acc = b1[o];
        float4 q0 = wr[0];
        acc = fmaf(q0.x, gx, acc);
        acc = fmaf(q0.y, gy, acc);
        acc = fmaf(q0.z, gz, acc);
        acc = fmaf(q0.w, fin[0], acc);
#pragma unroll
        for (int j = 1; j < 17; ++j) {
            float4 q = wr[j];
            int c0 = 4 * j - 3;
            acc = fmaf(q.x, fin[c0], acc);
            acc = fmaf(q.y, fin[c0 + 1], acc);
            acc = fmaf(q.z, fin[c0 + 2], acc);
            if (c0 + 3 < 64) acc = fmaf(q.w, fin[c0 + 3], acc);
        }
        h1[o] = fmaxf(acc, 0.0f);
    }

    float h2[64];
#pragma unroll
    for (int o = 0; o < 64; ++o) {
        const float4* wr = (const float4*)(w2 + o * 64);
        float acc = b2[o];
#pragma unroll
        for (int j = 0; j < 16; ++j) {
            float4 q = wr[j];
            acc = fmaf(q.x, h1[4 * j], acc);
            acc = fmaf(q.y, h1[4 * j + 1], acc);
            acc = fmaf(q.z, h1[4 * j + 2], acc);
            acc = fmaf(q.w, h1[4 * j + 3], acc);
        }
        h2[o] = fmaxf(acc, 0.0f);
    }

    float* ob = out + (size_t)b * 128 * NPOINT + p;
#pragma unroll
    for (int o = 0; o < 128; ++o) {
        const float4* wr = (const float4*)(w3 + o * 64);
        float acc = b3[o];
#pragma unroll
        for (int j = 0; j < 16; ++j) {
            float4 q = wr[j];
            acc = fmaf(q.x, h2[4 * j], acc);
            acc = fmaf(q.y, h2[4 * j + 1], acc);
            acc = fmaf(q.z, h2[4 * j + 2], acc);
            acc = fmaf(q.w, h2[4 * j + 3], acc);
        }
        float r = fmaxf(acc, 0.0f);
#pragma unroll
        for (int off = 1; off < 32; off <<= 1) {
            float orr = __shfl_xor(r, off);
            r = fmaxf(r, orr);
        }
        if (s == 0) ob[(size_t)o * NPOINT] = r;
    }
}

extern "C" void kernel_launch(void* const* d_in, const int* in_sizes, int n_in,
                              void* d_out, int out_size, void* d_ws, size_t ws_size,
                              hipStream_t stream) {
    const float* xyz = (const float*)d_in[0];
    const float* features = (const float*)d_in[1];
    const float* w1 = (const float*)d_in[2];
    const float* b1 = (const float*)d_in[3];
    const float* w2 = (const float*)d_in[4];
    const float* b2 = (const float*)d_in[5];
    const float* w3 = (const float*)d_in[6];
    const float* b3 = (const float*)d_in[7];

    float* out = (float*)d_out;
    float* new_xyz = out;                          // B*NPOINT*3
    float* new_feat = out + BB * NPOINT * 3;       // B*128*NPOINT

    int* nidx = (int*)d_ws;                        // B*NPOINT*NSAMPLE ints (512 KiB)
    float* w1p = (float*)((char*)d_ws + (size_t)BB * NPOINT * NSAMPLE * sizeof(int));
    unsigned long long* slots = (unsigned long long*)((char*)d_ws
                                + (size_t)BB * NPOINT * NSAMPLE * sizeof(int)
                                + (size_t)64 * 68 * sizeof(float));  // 8B-aligned

    hipLaunchKernelGGL(repack_w1, dim3(1), dim3(256), 0, stream, w1, w1p, slots);
    hipLaunchKernelGGL(fps_kernel, dim3(BB * FKB), dim3(FWT), 0, stream,
                       xyz, new_xyz, slots);
    hipLaunchKernelGGL(ballquery_kernel, dim3(BB * NPOINT / 4), dim3(256), 0, stream,
                       xyz, new_xyz, nidx);
    hipLaunchKernelGGL(mlp_kernel, dim3(BB * NPOINT * NSAMPLE / 256), dim3(256), 0, stream,
                       xyz, features, new_xyz, nidx, w1p, b1, w2, b2, w3, b3, new_feat);
}